// Round 1
// 552.415 us; speedup vs baseline: 1.7426x; 1.7426x over previous
//
#include <hip/hip_runtime.h>
#include <hip/hip_bf16.h>

// Problem constants
static constexpr int B   = 64;
static constexpr int CIN = 2048;
static constexpr int O   = 256;    // out channels = d
static constexpr int HW  = 196;    // 14*14 = M
static constexpr int D   = 256;    // matrix dim
static constexpr int TRI = 32896;  // D*(D+1)/2
static constexpr int NQ_COUPLED = 5; // coupled iters AFTER the identity iter0
static constexpr int NTILE = 10;   // upper-triangular 64x64 tiles of 256x256
static constexpr size_t NELEM = (size_t)B * D * D;   // 4,194,304
static constexpr size_t YN    = (size_t)B * O * HW;  // 3,211,264

typedef unsigned short u16;
typedef unsigned short u16x8 __attribute__((ext_vector_type(8)));
typedef __bf16         bf16x8 __attribute__((ext_vector_type(8)));
typedef float          f32x4 __attribute__((ext_vector_type(4)));

__constant__ int c_TI[NTILE] = {0,0,0,0,1,1,1,2,2,3};
__constant__ int c_TJ[NTILE] = {0,1,2,3,1,2,3,2,3,3};

static __device__ __forceinline__ u16 f2bf(float x) {
    unsigned int u = __float_as_uint(x);
    u += 0x7FFFu + ((u >> 16) & 1u);          // round-to-nearest-even
    return (u16)(u >> 16);
}
static __device__ __forceinline__ float bf2f(u16 h) {
    return __uint_as_float(((unsigned int)h) << 16);
}
static __device__ __forceinline__ f32x4 mm_bf16(u16x8 a, u16x8 b, f32x4 c) {
    return __builtin_amdgcn_mfma_f32_16x16x32_bf16(
        __builtin_bit_cast(bf16x8, a), __builtin_bit_cast(bf16x8, b), c, 0, 0, 0);
}

// ---------------------------------------------------------------------------
// K0: split W fp32 -> bf16 (Wh, Wl) planes, once
// ---------------------------------------------------------------------------
__global__ __launch_bounds__(256) void k_wsplit(const float* __restrict__ W,
                                                u16* __restrict__ Wh,
                                                u16* __restrict__ Wl) {
    const size_t i = (size_t)blockIdx.x * 256 + threadIdx.x;
    const float v = W[i];
    const u16 h = f2bf(v);
    Wh[i] = h;
    Wl[i] = f2bf(v - bf2f(h));
}

// ---------------------------------------------------------------------------
// K1: conv via bf16 MFMA 2-plane split (round-17 proven, ~110us)
// ---------------------------------------------------------------------------
__global__ __launch_bounds__(256) void k_conv(const float* __restrict__ x,
                                              const u16* __restrict__ Wh,
                                              const u16* __restrict__ Wl,
                                              float* __restrict__ psum) {
    const int l   = blockIdx.x;
    const int xcd = l & 7, idx = l >> 3;
    const int p   = xcd + 8 * (idx >> 2);   // 0..783
    const int ot  = idx & 3;
    const int ct  = p >> 2, ks = p & 3;
    const int o0  = ot * 64;
    const int cbase = ks * 512;
    float* yp = psum + (size_t)ks * YN;

    const int tid = threadIdx.x;

    __shared__ u16 sWh[64][40], sWl[64][40];
    __shared__ u16 sXh[64][40], sXl[64][40];
    __shared__ int s_coff[64];
    __shared__ int s_yoff[64];

    if (tid < 64) {
        const int g = ct * 64 + tid;
        const int b = g / 196;
        const int m = g - b * 196;
        s_coff[tid] = b * (CIN * HW) + m;
        s_yoff[tid] = b * (O * HW) + m;
    }
    __syncthreads();

    const int rW  = tid >> 2, kqW = (tid & 3) << 3;
    const int cX  = tid & 63, kqX = (tid >> 6) << 3;
    const int cofX = s_coff[cX];

    const int lane = tid & 63, w = tid >> 6;
    const int wr = w >> 1, wc = w & 1;
    const int lr = lane & 15, lg = lane >> 4;

    const f32x4 z4 = {0.f, 0.f, 0.f, 0.f};
    f32x4 acc00 = z4, acc01 = z4, acc10 = z4, acc11 = z4;

    for (int kb = 0; kb < 512; kb += 32) {
        {
            const size_t g = (size_t)(o0 + rW) * CIN + cbase + kb + kqW;
            *(u16x8*)&sWh[rW][kqW] = *(const u16x8*)&Wh[g];
            *(u16x8*)&sWl[rW][kqW] = *(const u16x8*)&Wl[g];
        }
        {
            u16x8 vh, vl;
            #pragma unroll
            for (int i = 0; i < 8; ++i) {
                const float v = x[(size_t)(cbase + kb + kqX + i) * HW + cofX];
                const u16 h = f2bf(v);
                vh[i] = h;
                vl[i] = f2bf(v - bf2f(h));
            }
            *(u16x8*)&sXh[cX][kqX] = vh;
            *(u16x8*)&sXl[cX][kqX] = vl;
        }
        __syncthreads();

        const int ra = wr * 32 + lr, rb = wc * 32 + lr;
        const int ko = lg << 3;
        const u16x8 a0h = *(const u16x8*)&sWh[ra][ko];
        const u16x8 a0l = *(const u16x8*)&sWl[ra][ko];
        const u16x8 a1h = *(const u16x8*)&sWh[ra + 16][ko];
        const u16x8 a1l = *(const u16x8*)&sWl[ra + 16][ko];
        const u16x8 b0h = *(const u16x8*)&sXh[rb][ko];
        const u16x8 b0l = *(const u16x8*)&sXl[rb][ko];
        const u16x8 b1h = *(const u16x8*)&sXh[rb + 16][ko];
        const u16x8 b1l = *(const u16x8*)&sXl[rb + 16][ko];

        acc00 = mm_bf16(a0h, b0h, acc00);
        acc00 = mm_bf16(a0h, b0l, acc00);
        acc00 = mm_bf16(a0l, b0h, acc00);
        acc01 = mm_bf16(a0h, b1h, acc01);
        acc01 = mm_bf16(a0h, b1l, acc01);
        acc01 = mm_bf16(a0l, b1h, acc01);
        acc10 = mm_bf16(a1h, b0h, acc10);
        acc10 = mm_bf16(a1h, b0l, acc10);
        acc10 = mm_bf16(a1l, b0h, acc10);
        acc11 = mm_bf16(a1h, b1h, acc11);
        acc11 = mm_bf16(a1h, b1l, acc11);
        acc11 = mm_bf16(a1l, b1h, acc11);
        __syncthreads();
    }

    auto epi = [&](const f32x4& a, int fi, int fj) {
        const int orow0 = o0 + wr * 32 + fi * 16 + (lg << 2);
        const int col   = wc * 32 + fj * 16 + lr;
        const int yo = s_yoff[col];
        #pragma unroll
        for (int r = 0; r < 4; ++r)
            yp[(size_t)(orow0 + r) * HW + yo] = a[r];
    };
    epi(acc00, 0, 0); epi(acc01, 0, 1); epi(acc10, 1, 0); epi(acc11, 1, 1);
}

// ---------------------------------------------------------------------------
// K1b: y = psum0+psum1+psum2+psum3  (float4)
// ---------------------------------------------------------------------------
__global__ __launch_bounds__(256) void k_redy(const float* __restrict__ ps,
                                              float* __restrict__ y) {
    const size_t i = ((size_t)blockIdx.x * 256 + threadIdx.x) * 4;
    if (i >= YN) return;
    float4 a = *(const float4*)&ps[i];
    const float4 b = *(const float4*)&ps[YN + i];
    const float4 c = *(const float4*)&ps[2 * YN + i];
    const float4 d = *(const float4*)&ps[3 * YN + i];
    a.x += b.x + c.x + d.x; a.y += b.y + c.y + d.y;
    a.z += b.z + c.z + d.z; a.w += b.w + c.w + d.w;
    *(float4*)&y[i] = a;
}

// ---------------------------------------------------------------------------
// K2: BN stats per channel
// ---------------------------------------------------------------------------
__global__ __launch_bounds__(256) void k_bnstats(const float* __restrict__ y,
                                                 const float* __restrict__ gamma,
                                                 const float* __restrict__ beta,
                                                 float* __restrict__ scl,
                                                 float* __restrict__ shf) {
    const int o = blockIdx.x;
    const int tid = threadIdx.x;
    float s = 0.f, s2 = 0.f;
    if (tid < HW) {
        for (int b = 0; b < B; ++b) {
            const float v = y[((size_t)b * O + o) * HW + tid];
            s += v; s2 += v * v;
        }
    }
    #pragma unroll
    for (int msk = 32; msk; msk >>= 1) {
        s  += __shfl_xor(s,  msk);
        s2 += __shfl_xor(s2, msk);
    }
    __shared__ float rs[4], rs2[4];
    if ((tid & 63) == 0) { rs[tid >> 6] = s; rs2[tid >> 6] = s2; }
    __syncthreads();
    if (tid == 0) {
        const float N = (float)(B * HW);
        const float ts  = rs[0] + rs[1] + rs[2] + rs[3];
        const float ts2 = rs2[0] + rs2[1] + rs2[2] + rs2[3];
        const float mean = ts / N;
        const float var  = ts2 / N - mean * mean;
        const float sc = gamma[o] * rsqrtf(var + 1e-5f);
        scl[o] = sc;
        shf[o] = beta[o] - mean * sc;
    }
}

// ---------------------------------------------------------------------------
// K3: z = relu(y*scale+shift); zc = z - rowmean(z)
// ---------------------------------------------------------------------------
__global__ __launch_bounds__(64) void k_center(float* __restrict__ z,
                                               const float* __restrict__ scl,
                                               const float* __restrict__ shf) {
    const int row = blockIdx.x;
    const int o = row & 255;
    const int lane = threadIdx.x;
    const float sc = scl[o], sh = shf[o];
    float* zr = &z[(size_t)row * HW];
    float vals[4];
    float s = 0.f;
    #pragma unroll
    for (int q = 0; q < 4; ++q) {
        const int m = q * 64 + lane;
        float v = 0.f;
        if (m < HW) v = fmaxf(fmaf(zr[m], sc, sh), 0.f);
        vals[q] = v; s += v;
    }
    #pragma unroll
    for (int msk = 32; msk; msk >>= 1) s += __shfl_xor(s, msk);
    const float mean = s / (float)HW;
    #pragma unroll
    for (int q = 0; q < 4; ++q) {
        const int m = q * 64 + lane;
        if (m < HW) zr[m] = vals[q] - mean;
    }
}

// ---------------------------------------------------------------------------
// K4: cov[b] = zc zc^T / M   (fp64 accumulation — PSD to ~1e-13)
// ---------------------------------------------------------------------------
__global__ __launch_bounds__(256) void k_cov(const float* __restrict__ z,
                                             double* __restrict__ cov) {
    const int b = blockIdx.y;
    const int jt = blockIdx.x & 3, it = blockIdx.x >> 2;
    const int i0 = it * 64, j0 = jt * 64;
    const int tid = threadIdx.x;
    const int tn = tid & 15, tmq = tid >> 4;

    __shared__ float sA[28][68], sB[28][68];
    double acc[4][4] = {};
    const float* zb = &z[(size_t)b * D * HW];

    for (int k0 = 0; k0 < HW; k0 += 28) {
        #pragma unroll
        for (int q = 0; q < 7; ++q) {
            const int idx = tid + q * 256;
            const int r = idx / 28, kk = idx % 28;
            sA[kk][r] = zb[(size_t)(i0 + r) * HW + k0 + kk];
            sB[kk][r] = zb[(size_t)(j0 + r) * HW + k0 + kk];
        }
        __syncthreads();
        #pragma unroll
        for (int kk = 0; kk < 28; ++kk) {
            const float4 av = *reinterpret_cast<const float4*>(&sA[kk][tmq << 2]);
            const float4 bv = *reinterpret_cast<const float4*>(&sB[kk][tn << 2]);
            const double aa[4] = {av.x, av.y, av.z, av.w};
            const double bb[4] = {bv.x, bv.y, bv.z, bv.w};
            #pragma unroll
            for (int i = 0; i < 4; ++i)
                #pragma unroll
                for (int j = 0; j < 4; ++j)
                    acc[i][j] = fma(aa[i], bb[j], acc[i][j]);
        }
        __syncthreads();
    }
    const double inv = 1.0 / (double)HW;
    #pragma unroll
    for (int i = 0; i < 4; ++i)
        #pragma unroll
        for (int j = 0; j < 4; ++j)
            cov[(size_t)b * D * D + (size_t)(i0 + (tmq << 2) + i) * D
                + j0 + (tn << 2) + j] = acc[i][j] * inv;
}

// ---------------------------------------------------------------------------
// K5: spectral-norm estimate, 6 power iterations (proven)
// ---------------------------------------------------------------------------
__global__ __launch_bounds__(256) void k_lmax(const double* __restrict__ cov,
                                              double* __restrict__ cn) {
    const int b = blockIdx.x;
    const int tid = threadIdx.x;
    const double* A = &cov[(size_t)b * D * D];
    __shared__ double v[256];
    __shared__ double red[4];
    v[tid] = 1.0;
    __syncthreads();
    double lam = 1.0;
    for (int it = 0; it < 6; ++it) {
        const double* row = &A[(size_t)tid * D];
        double u0 = 0.0, u1 = 0.0;
        #pragma unroll 16
        for (int k = 0; k < D; k += 2) {
            const double2 rv = *(const double2*)&row[k];
            u0 = fma(rv.x, v[k], u0);
            u1 = fma(rv.y, v[k + 1], u1);
        }
        const double u = u0 + u1;
        double s = u * u;
        #pragma unroll
        for (int msk = 32; msk; msk >>= 1) s += __shfl_xor(s, msk);
        if ((tid & 63) == 0) red[tid >> 6] = s;
        __syncthreads();
        const double nrm = sqrt(red[0] + red[1] + red[2] + red[3]) + 1e-300;
        lam = nrm;
        __syncthreads();
        v[tid] = u / nrm;
        __syncthreads();
    }
    if (tid == 0) cn[b] = (lam > 1e-30) ? 1.25 * lam : 1.0;
}

// ---------------------------------------------------------------------------
// K6: Y0 planes = bf16-split fp32(cov / c_b + 1e-7*I), FULL matrix
//     (the MFMA gemms read full symmetric matrices; mirror tiles of cov are
//     bit-identical by k_cov's construction).
// ---------------------------------------------------------------------------
__global__ __launch_bounds__(256) void k_init(const double* __restrict__ cov,
                                              const double* __restrict__ cn,
                                              u16* __restrict__ Yh,
                                              u16* __restrict__ Yl) {
    const size_t e = (size_t)blockIdx.x * 256 + threadIdx.x;
    const int b = (int)(e >> 16);
    const int ij = (int)(e & 65535);
    const int i = ij >> 8, j = ij & 255;
    const double diag = (i == j) ? 1e-7 : 0.0;
    const float f = (float)(cov[e] / cn[b] + diag);
    const u16 h = f2bf(f);
    Yh[e] = h;
    Yl[e] = f2bf(f - bf2f(h));
}

// ---------------------------------------------------------------------------
// K7: bf16-MFMA symmetric gemm on hi/lo planes, 64x64 tiles, 256 threads,
//     double-buffered LDS + register prefetch. All operands are symmetric
//     and FULLY materialized (upper tiles computed, lower tiles mirrored in
//     the epilogue via an LDS transpose), so every staging load is a plain
//     coalesced u16x8 copy (no transposed reads, no fp32->bf16 conversion
//     in the K-loop). Products use the 2-plane split: ah*bh + ah*bl + al*bh.
//       MODE 1: C = (15I - 10*A + 3*A*B)/8 = q(A) (A==B, reads A at out)
//       MODE 2: C = A*B
//       MODE 3: out[tri] = sqrt(cn)*(A*B) upper triangle (extract fold)
// ---------------------------------------------------------------------------
template <int MODE, int FUSED>
__global__ __launch_bounds__(256) void k_mgemm(
        const u16* __restrict__ A0h, const u16* __restrict__ A0l,
        const u16* __restrict__ B0h, const u16* __restrict__ B0l,
        u16* __restrict__ C0h, u16* __restrict__ C0l,
        const u16* __restrict__ A1h, const u16* __restrict__ A1l,
        const u16* __restrict__ B1h, const u16* __restrict__ B1l,
        u16* __restrict__ C1h, u16* __restrict__ C1l,
        const double* __restrict__ cn, float* __restrict__ outp) {
    const int orig = blockIdx.x;
    const int xcd  = orig & 7;
    const int s    = orig >> 3;
    int batch, tile, opz;
    if (FUSED) {
        const int bl  = s / 20;
        const int rem = s - bl * 20;
        opz  = rem >= 10;
        tile = rem - opz * 10;
        batch = xcd * 8 + bl;
    } else {
        opz = 0;
        batch = xcd * 8 + s / 10;
        tile = s - (s / 10) * 10;
    }

    const u16 *Ah, *Al, *Bh, *Bl;
    u16 *Ch, *Cl;
    if (opz == 0) { Ah = A0h; Al = A0l; Bh = B0h; Bl = B0l; Ch = C0h; Cl = C0l; }
    else          { Ah = A1h; Al = A1l; Bh = B1h; Bl = B1l; Ch = C1h; Cl = C1l; }

    const int it = c_TI[tile], jt = c_TJ[tile];
    const int i0 = it * 64, j0 = jt * 64;
    const size_t boff = (size_t)batch * 65536;
    Ah += boff; Al += boff; Bh += boff; Bl += boff; Ch += boff; Cl += boff;

    const int tid = threadIdx.x;
    __shared__ u16 sA[2][2][64][40];   // [buf][hi/lo][row][k]
    __shared__ u16 sB[2][2][64][40];

    const int rW = tid >> 2, kq = (tid & 3) << 3;
    const u16* gAh = Ah + (size_t)(i0 + rW) * 256 + kq;
    const u16* gAl = Al + (size_t)(i0 + rW) * 256 + kq;
    // B read as rows of its symmetric self: B[k][j] == B[j][k]
    const u16* gBh = Bh + (size_t)(j0 + rW) * 256 + kq;
    const u16* gBl = Bl + (size_t)(j0 + rW) * 256 + kq;

    const int lane = tid & 63, w = tid >> 6;
    const int wr = w >> 1, wc = w & 1;
    const int lr = lane & 15, lg = lane >> 4, ko = lg << 3;
    const int ra = wr * 32 + lr, rb = wc * 32 + lr;

    const f32x4 z4 = {0.f, 0.f, 0.f, 0.f};
    f32x4 acc00 = z4, acc01 = z4, acc10 = z4, acc11 = z4;

    *(u16x8*)&sA[0][0][rW][kq] = *(const u16x8*)&gAh[0];
    *(u16x8*)&sA[0][1][rW][kq] = *(const u16x8*)&gAl[0];
    *(u16x8*)&sB[0][0][rW][kq] = *(const u16x8*)&gBh[0];
    *(u16x8*)&sB[0][1][rW][kq] = *(const u16x8*)&gBl[0];
    __syncthreads();

    int cur = 0;
    #pragma unroll
    for (int st = 0; st < 8; ++st) {
        u16x8 nAh, nAl, nBh, nBl;
        if (st < 7) {
            const int k1 = (st + 1) << 5;
            nAh = *(const u16x8*)&gAh[k1];
            nAl = *(const u16x8*)&gAl[k1];
            nBh = *(const u16x8*)&gBh[k1];
            nBl = *(const u16x8*)&gBl[k1];
        }
        const u16x8 a0h = *(const u16x8*)&sA[cur][0][ra][ko];
        const u16x8 a0l = *(const u16x8*)&sA[cur][1][ra][ko];
        const u16x8 a1h = *(const u16x8*)&sA[cur][0][ra + 16][ko];
        const u16x8 a1l = *(const u16x8*)&sA[cur][1][ra + 16][ko];
        const u16x8 b0h = *(const u16x8*)&sB[cur][0][rb][ko];
        const u16x8 b0l = *(const u16x8*)&sB[cur][1][rb][ko];
        const u16x8 b1h = *(const u16x8*)&sB[cur][0][rb + 16][ko];
        const u16x8 b1l = *(const u16x8*)&sB[cur][1][rb + 16][ko];

        acc00 = mm_bf16(a0h, b0h, acc00);
        acc00 = mm_bf16(a0h, b0l, acc00);
        acc00 = mm_bf16(a0l, b0h, acc00);
        acc01 = mm_bf16(a0h, b1h, acc01);
        acc01 = mm_bf16(a0h, b1l, acc01);
        acc01 = mm_bf16(a0l, b1h, acc01);
        acc10 = mm_bf16(a1h, b0h, acc10);
        acc10 = mm_bf16(a1h, b0l, acc10);
        acc10 = mm_bf16(a1l, b0h, acc10);
        acc11 = mm_bf16(a1h, b1h, acc11);
        acc11 = mm_bf16(a1h, b1l, acc11);
        acc11 = mm_bf16(a1l, b1h, acc11);

        if (st < 7) {
            *(u16x8*)&sA[cur ^ 1][0][rW][kq] = nAh;
            *(u16x8*)&sA[cur ^ 1][1][rW][kq] = nAl;
            *(u16x8*)&sB[cur ^ 1][0][rW][kq] = nBh;
            *(u16x8*)&sB[cur ^ 1][1][rW][kq] = nBl;
        }
        __syncthreads();
        cur ^= 1;
    }

    // ---- epilogue ----
    const f32x4 accs[2][2] = {{acc00, acc01}, {acc10, acc11}};
    const int orow = wr * 32 + (lg << 2);
    const int ocol = wc * 32 + lr;

    if (MODE == 3) {
        const double sc = sqrt(cn[batch]);
        #pragma unroll
        for (int fi = 0; fi < 2; ++fi)
            #pragma unroll
            for (int r = 0; r < 4; ++r) {
                const int gi = i0 + orow + fi * 16 + r;
                const size_t rowoff = (size_t)gi * D - ((size_t)gi * (gi - 1)) / 2;
                #pragma unroll
                for (int fj = 0; fj < 2; ++fj) {
                    const int gj = j0 + ocol + fj * 16;
                    if (gj >= gi)
                        outp[(size_t)batch * TRI + rowoff + (gj - gi)] =
                            (float)(sc * (double)accs[fi][fj][r]);
                }
            }
        return;
    }

    u16 hv[2][4][2], lv[2][4][2];
    #pragma unroll
    for (int fi = 0; fi < 2; ++fi)
        #pragma unroll
        for (int r = 0; r < 4; ++r) {
            const int li = orow + fi * 16 + r;
            const int gi = i0 + li;
            #pragma unroll
            for (int fj = 0; fj < 2; ++fj) {
                const int gj = j0 + ocol + fj * 16;
                float v = accs[fi][fj][r];
                if (MODE == 1) {
                    const size_t xo = (size_t)gi * 256 + gj;
                    const float xv = bf2f(Ah[xo]) + bf2f(Al[xo]);   // A == M here
                    v = (((gi == gj) ? 15.0f : 0.0f) - 10.0f * xv + 3.0f * v) * 0.125f;
                }
                const u16 h = f2bf(v);
                const u16 l = f2bf(v - bf2f(h));
                const size_t co = (size_t)gi * 256 + gj;
                Ch[co] = h;
                Cl[co] = l;
                hv[fi][r][fj] = h;
                lv[fi][r][fj] = l;
            }
        }

    if (it != jt) {
        // mirror write C[j][i] = C[i][j] via LDS transpose (coalesced out)
        u16 (*tH)[72] = reinterpret_cast<u16(*)[72]>(&sA[0][0][0][0]);
        u16 (*tL)[72] = reinterpret_cast<u16(*)[72]>(&sB[0][0][0][0]);
        #pragma unroll
        for (int fi = 0; fi < 2; ++fi)
            #pragma unroll
            for (int r = 0; r < 4; ++r) {
                const int li = orow + fi * 16 + r;
                #pragma unroll
                for (int fj = 0; fj < 2; ++fj) {
                    const int lj = ocol + fj * 16;
                    tH[lj][li] = hv[fi][r][fj];
                    tL[lj][li] = lv[fi][r][fj];
                }
            }
        __syncthreads();
        const int r2 = tid >> 2, c2 = (tid & 3) << 4;
        const size_t mo = (size_t)(j0 + r2) * 256 + i0 + c2;
        *(u16x8*)&Ch[mo]     = *(const u16x8*)&tH[r2][c2];
        *(u16x8*)&Ch[mo + 8] = *(const u16x8*)&tH[r2][c2 + 8];
        *(u16x8*)&Cl[mo]     = *(const u16x8*)&tL[r2][c2];
        *(u16x8*)&Cl[mo + 8] = *(const u16x8*)&tL[r2][c2 + 8];
    }
}

// ---------------------------------------------------------------------------
extern "C" void kernel_launch(void* const* d_in, const int* in_sizes, int n_in,
                              void* d_out, int out_size, void* d_ws, size_t ws_size,
                              hipStream_t stream) {
    const float* x     = (const float*)d_in[0];
    const float* W     = (const float*)d_in[1];
    const float* gamma = (const float*)d_in[2];
    const float* beta  = (const float*)d_in[3];
    float* out = (float*)d_out;

    char* ws = (char*)d_ws;
    size_t off = 0;
    auto alloc = [&](size_t bytes) -> void* {
        void* p = ws + off;
        off += (bytes + 255) & ~(size_t)255;
        return p;
    };
    float*  y    = (float*)alloc(YN * sizeof(float));
    double* cov  = (double*)alloc(NELEM * sizeof(double));
    float*  scl  = (float*)alloc(O * sizeof(float));
    float*  shf  = (float*)alloc(O * sizeof(float));
    double* cn   = (double*)alloc(B * sizeof(double));
    u16*    Wh   = (u16*)alloc((size_t)O * CIN * sizeof(u16));
    u16*    Wl   = (u16*)alloc((size_t)O * CIN * sizeof(u16));
    // 12 bf16 planes for the Z-free Newton-Schulz chain (Y/M ping-pong, R, U)
    u16* pl = (u16*)alloc(12 * NELEM * sizeof(u16));
    if (off > ws_size) return;
    u16 *YAh = pl,             *YAl = pl + NELEM;
    u16 *YBh = pl + 2 * NELEM, *YBl = pl + 3 * NELEM;
    u16 *MAh = pl + 4 * NELEM, *MAl = pl + 5 * NELEM;
    u16 *MBh = pl + 6 * NELEM, *MBl = pl + 7 * NELEM;
    u16 *Rh  = pl + 8 * NELEM, *Rl  = pl + 9 * NELEM;
    u16 *Uh  = pl + 10 * NELEM,*Ul  = pl + 11 * NELEM;
    float* psum = (float*)pl;   // conv partials alias the plane block (dead until k_init)

    k_wsplit <<<(O * CIN) / 256, 256, 0, stream>>>(W, Wh, Wl);
    k_conv   <<<3136, 256, 0, stream>>>(x, Wh, Wl, psum);
    k_redy   <<<3136, 256, 0, stream>>>(psum, y);
    k_bnstats<<<O, 256, 0, stream>>>(y, gamma, beta, scl, shf);
    k_center <<<B * O, 64, 0, stream>>>(y, scl, shf);
    k_cov    <<<dim3(16, B), 256, 0, stream>>>(y, cov);
    k_lmax   <<<B, 256, 0, stream>>>(cov, cn);
    k_init   <<<B * 256, 256, 0, stream>>>(cov, cn, YAh, YAl);

    // Z-free coupled Newton-Schulz: M = Z*Y tracked directly.
    //   R = q(M); Y' = Y*R; M' = R*(M*R).  (identical eigen-recursion to the
    //   Z-form, but every iterate stays O(1) — no 1.875^k null-space blowup)
    // ---- iteration 0 (M0 == Y0):
    k_mgemm<1, 0><<<640, 256, 0, stream>>>(YAh, YAl, YAh, YAl, Rh, Rl,
                                           YAh, YAl, YAh, YAl, Rh, Rl, cn, out);
    k_mgemm<2, 0><<<640, 256, 0, stream>>>(YAh, YAl, Rh, Rl, YBh, YBl,
                                           YAh, YAl, Rh, Rl, YBh, YBl, cn, out);
    k_mgemm<2, 0><<<640, 256, 0, stream>>>(Rh, Rl, YBh, YBl, MBh, MBl,
                                           Rh, Rl, YBh, YBl, MBh, MBl, cn, out);

    u16 *Ych = YBh, *Ycl = YBl, *Yah = YAh, *Yal = YAl;
    u16 *Mch = MBh, *Mcl = MBl, *Mah = MAh, *Mal = MAl;
    for (int itq = 0; itq < NQ_COUPLED; ++itq) {
        // R = q(Mc)
        k_mgemm<1, 0><<<640, 256, 0, stream>>>(Mch, Mcl, Mch, Mcl, Rh, Rl,
                                               Mch, Mcl, Mch, Mcl, Rh, Rl, cn, out);
        // fused: Ya = Yc*R ; U = Mc*R
        k_mgemm<2, 1><<<1280, 256, 0, stream>>>(Ych, Ycl, Rh, Rl, Yah, Yal,
                                                Mch, Mcl, Rh, Rl, Uh, Ul, cn, out);
        // Ma = R*U = R*Mc*R
        k_mgemm<2, 0><<<640, 256, 0, stream>>>(Rh, Rl, Uh, Ul, Mah, Mal,
                                               Rh, Rl, Uh, Ul, Mah, Mal, cn, out);
        u16* t;
        t = Ych; Ych = Yah; Yah = t;  t = Ycl; Ycl = Yal; Yal = t;
        t = Mch; Mch = Mah; Mah = t;  t = Mcl; Mcl = Mal; Mal = t;
    }
    // final: R = q(Mc); out = sqrt(cn) * (Yc*R) upper triangle
    k_mgemm<1, 0><<<640, 256, 0, stream>>>(Mch, Mcl, Mch, Mcl, Rh, Rl,
                                           Mch, Mcl, Mch, Mcl, Rh, Rl, cn, out);
    k_mgemm<3, 0><<<640, 256, 0, stream>>>(Ych, Ycl, Rh, Rl, Uh, Ul,
                                           Ych, Ycl, Rh, Rl, Uh, Ul, cn, out);
}